// Round 1
// baseline (505.252 us; speedup 1.0000x reference)
//
#include <hip/hip_runtime.h>
#include <math.h>

#define BS 8
#define NPTS 16384
#define C 32
#define K 256
#define KNNK 16
#define KT 16          // keypoints per phase-1 block
#define NSPLIT 4       // n-chunks per (b, ktile)
#define CHUNK (NPTS/NSPLIT)   // 4096
#define NBINS 512
#define BINW 0.00025f

// ---------------------------------------------------------------------------
// Phase 1: fused regression-logit GEMM + exp + weighted position accumulation.
// Softmax bias from the pooling head is constant over n and cancels in the
// per-graph softmax, so W_pool / glob / batched are never computed.
// Logits are bounded (~|L|<4) so exp() without max-subtraction cannot overflow;
// partial sums merge trivially across blocks.
// ---------------------------------------------------------------------------
__global__ __launch_bounds__(256, 2) void k_logits(
    const float* __restrict__ f, const float* __restrict__ pos,
    const float* __restrict__ Wr, float* __restrict__ partials) {
  __shared__ float4 Wl[KT * 8];  // [k][c4], read as wave-uniform broadcast
  int tid = threadIdx.x;
  int blk = blockIdx.x;
  int b = blk >> 6;       // 64 blocks per graph
  int r = blk & 63;
  int ktile = r >> 2;     // 16 keypoint tiles
  int split = r & 3;      // 4 n-splits

  float* Wls = (float*)Wl;
  for (int t = tid; t < KT * C; t += 256) {
    int kl = t & (KT - 1);
    int c = t >> 4;
    Wls[kl * C + c] = Wr[c * K + ktile * KT + kl];
  }
  __syncthreads();

  float accl[KT], accx[KT], accy[KT], accz[KT];
#pragma unroll
  for (int k = 0; k < KT; k++) { accl[k] = 0.f; accx[k] = 0.f; accy[k] = 0.f; accz[k] = 0.f; }

  int pbase = b * NPTS + split * CHUNK;
#pragma unroll 1
  for (int it = 0; it < 8; it++) {
    int p0 = pbase + 2 * it * 256 + tid;
    int p1 = p0 + 256;
    const float4* f0 = (const float4*)(f + (size_t)p0 * C);
    const float4* f1 = (const float4*)(f + (size_t)p1 * C);
    float4 a0[8], a1[8];
#pragma unroll
    for (int c4 = 0; c4 < 8; c4++) { a0[c4] = f0[c4]; a1[c4] = f1[c4]; }
    float p0x = pos[p0 * 3 + 0], p0y = pos[p0 * 3 + 1], p0z = pos[p0 * 3 + 2];
    float p1x = pos[p1 * 3 + 0], p1y = pos[p1 * 3 + 1], p1z = pos[p1 * 3 + 2];
#pragma unroll
    for (int k = 0; k < KT; k++) {
      float l0 = 0.f, l1 = 0.f;
#pragma unroll
      for (int c4 = 0; c4 < 8; c4++) {
        float4 w = Wl[k * 8 + c4];
        l0 += a0[c4].x * w.x + a0[c4].y * w.y + a0[c4].z * w.z + a0[c4].w * w.w;
        l1 += a1[c4].x * w.x + a1[c4].y * w.y + a1[c4].z * w.z + a1[c4].w * w.w;
      }
      float e0 = __expf(l0), e1 = __expf(l1);
      accl[k] += e0 + e1;
      accx[k] += e0 * p0x + e1 * p1x;
      accy[k] += e0 * p0y + e1 * p1y;
      accz[k] += e0 * p0z + e1 * p1z;
    }
  }

  int lane = tid & 63;
  int wave = tid >> 6;
  __shared__ float wred[4][KT][4];
#pragma unroll
  for (int k = 0; k < KT; k++) {
    float vl = accl[k], vx = accx[k], vy = accy[k], vz = accz[k];
#pragma unroll
    for (int off = 32; off; off >>= 1) {
      vl += __shfl_xor(vl, off, 64);
      vx += __shfl_xor(vx, off, 64);
      vy += __shfl_xor(vy, off, 64);
      vz += __shfl_xor(vz, off, 64);
    }
    if (lane == 0) {
      wred[wave][k][0] = vl; wred[wave][k][1] = vx;
      wred[wave][k][2] = vy; wred[wave][k][3] = vz;
    }
  }
  __syncthreads();
  if (tid < KT * 4) {
    int k = tid >> 2, comp = tid & 3;
    float s = wred[0][k][comp] + wred[1][k][comp] + wred[2][k][comp] + wred[3][k][comp];
    partials[((size_t)((b * K + ktile * KT + k) * NSPLIT + split)) * 4 + comp] = s;
  }
}

// ---------------------------------------------------------------------------
// Phase 1b: merge partials (fp64) -> keypoints; per-graph keypoint centroid +
// max diameter for the KNN candidate filter; zero hist / candidate counters.
// ---------------------------------------------------------------------------
__global__ __launch_bounds__(256) void k_centers(
    const float* __restrict__ partials, float* __restrict__ keypoints,
    float* __restrict__ centers, unsigned* __restrict__ hist,
    unsigned* __restrict__ cnt) {
  int b = blockIdx.x;
  int k = threadIdx.x;
  double L = 0, X = 0, Y = 0, Z = 0;
  for (int s = 0; s < NSPLIT; s++) {
    const float* p = partials + ((size_t)((b * K + k) * NSPLIT + s)) * 4;
    L += (double)p[0]; X += (double)p[1]; Y += (double)p[2]; Z += (double)p[3];
  }
  float kx = (float)(X / L), ky = (float)(Y / L), kz = (float)(Z / L);
  keypoints[(b * K + k) * 3 + 0] = kx;
  keypoints[(b * K + k) * 3 + 1] = ky;
  keypoints[(b * K + k) * 3 + 2] = kz;
  hist[b * NBINS + k] = 0;
  hist[b * NBINS + K + k] = 0;
  if (k == 0) cnt[b] = 0;

  __shared__ float red[256];
  red[k] = kx; __syncthreads();
  for (int s = 128; s; s >>= 1) { if (k < s) red[k] += red[k + s]; __syncthreads(); }
  float cx = red[0] / K; __syncthreads();
  red[k] = ky; __syncthreads();
  for (int s = 128; s; s >>= 1) { if (k < s) red[k] += red[k + s]; __syncthreads(); }
  float cy = red[0] / K; __syncthreads();
  red[k] = kz; __syncthreads();
  for (int s = 128; s; s >>= 1) { if (k < s) red[k] += red[k + s]; __syncthreads(); }
  float cz = red[0] / K; __syncthreads();
  float dx = kx - cx, dy = ky - cy, dz = kz - cz;
  red[k] = dx * dx + dy * dy + dz * dz; __syncthreads();
  for (int s = 128; s; s >>= 1) { if (k < s) red[k] = fmaxf(red[k], red[k + s]); __syncthreads(); }
  if (k == 0) {
    centers[b * 4 + 0] = cx; centers[b * 4 + 1] = cy; centers[b * 4 + 2] = cz;
    centers[b * 4 + 3] = sqrtf(red[0]);   // max dist keypoint->centroid
  }
}

// ---------------------------------------------------------------------------
// Phase 2a: histogram of d2(point, centroid) per graph.
// ---------------------------------------------------------------------------
__global__ __launch_bounds__(256) void k_hist(
    const float* __restrict__ pos, const float* __restrict__ centers,
    unsigned* __restrict__ hist) {
  __shared__ unsigned lh[NBINS];
  int b = blockIdx.x >> 3, part = blockIdx.x & 7;
  for (int t = threadIdx.x; t < NBINS; t += 256) lh[t] = 0;
  __syncthreads();
  float cx = centers[b * 4 + 0], cy = centers[b * 4 + 1], cz = centers[b * 4 + 2];
  for (int i = 0; i < 8; i++) {
    int p = b * NPTS + part * 2048 + i * 256 + threadIdx.x;
    float dx = pos[p * 3 + 0] - cx, dy = pos[p * 3 + 1] - cy, dz = pos[p * 3 + 2] - cz;
    float d2 = dx * dx + dy * dy + dz * dz;
    int bin = (int)(d2 * (1.0f / BINW));
    if (bin > NBINS - 1) bin = NBINS - 1;
    atomicAdd(&lh[bin], 1u);
  }
  __syncthreads();
  for (int t = threadIdx.x; t < NBINS; t += 256)
    if (lh[t]) atomicAdd(&hist[b * NBINS + t], lh[t]);
}

// ---------------------------------------------------------------------------
// Phase 2b: candidate radius. Exact bound: any point in some keypoint's top-16
// satisfies d(p,c) <= T + 2*maxdiam with T >= 16th-smallest d(.,c). Catch-all
// bin (T=inf) degenerates to keeping everything -> always correct.
// ---------------------------------------------------------------------------
__global__ void k_select(const unsigned* __restrict__ hist,
                         const float* __restrict__ centers,
                         float* __restrict__ Rf2) {
  int b = blockIdx.x;
  if (threadIdx.x == 0) {
    unsigned cum = 0; float T2 = 1e30f;
    for (int i = 0; i < NBINS; i++) {
      cum += hist[b * NBINS + i];
      if (cum >= KNNK) { T2 = (i + 1) * BINW; break; }
    }
    float Rf = sqrtf(T2) + 2.f * centers[b * 4 + 3];
    Rf2[b] = Rf * Rf;
  }
}

// ---------------------------------------------------------------------------
// Phase 2c: compact candidate indices (order irrelevant: KNN is a set).
// ---------------------------------------------------------------------------
__global__ __launch_bounds__(256) void k_compact(
    const float* __restrict__ pos, const float* __restrict__ centers,
    const float* __restrict__ Rf2, unsigned* __restrict__ cnt,
    int* __restrict__ cand) {
  int b = blockIdx.x >> 3, part = blockIdx.x & 7;
  float r2 = Rf2[b];
  float cx = centers[b * 4 + 0], cy = centers[b * 4 + 1], cz = centers[b * 4 + 2];
  for (int i = 0; i < 8; i++) {
    int pl = part * 2048 + i * 256 + threadIdx.x;
    int p = b * NPTS + pl;
    float dx = pos[p * 3 + 0] - cx, dy = pos[p * 3 + 1] - cy, dz = pos[p * 3 + 2] - cz;
    float d2 = dx * dx + dy * dy + dz * dz;
    if (d2 <= r2) {
      unsigned s = atomicAdd(&cnt[b], 1u);
      cand[b * NPTS + s] = pl;
    }
  }
}

// ---------------------------------------------------------------------------
// Phase 2d: exact top-16 (smallest d2) per keypoint over candidates.
// ---------------------------------------------------------------------------
__global__ __launch_bounds__(256) void k_knn(
    const float* __restrict__ pos, const float* __restrict__ keypoints,
    const unsigned* __restrict__ cnt, const int* __restrict__ cand,
    int* __restrict__ knn) {
  int b = blockIdx.x;
  int k = threadIdx.x;
  __shared__ float4 cp[1024];
  __shared__ int ci[1024];
  float kx = keypoints[(b * K + k) * 3 + 0];
  float ky = keypoints[(b * K + k) * 3 + 1];
  float kz = keypoints[(b * K + k) * 3 + 2];
  float dd[KNNK]; int ii[KNNK];
#pragma unroll
  for (int j = 0; j < KNNK; j++) { dd[j] = 1e30f; ii[j] = 0; }
  float mx = 1e30f;
  int n = (int)cnt[b];
  if (n > NPTS) n = NPTS;
  for (int c0 = 0; c0 < n; c0 += 1024) {
    int m = min(1024, n - c0);
    __syncthreads();
    for (int j = threadIdx.x; j < m; j += 256) {
      int pl = cand[b * NPTS + c0 + j];
      const float* pp = pos + (size_t)(b * NPTS + pl) * 3;
      cp[j] = make_float4(pp[0], pp[1], pp[2], 0.f);
      ci[j] = pl;
    }
    __syncthreads();
    for (int j = 0; j < m; j++) {
      float4 q = cp[j];
      float dx = kx - q.x, dy = ky - q.y, dz = kz - q.z;
      float d2 = dx * dx + dy * dy + dz * dz;
      if (d2 < mx) {
        int sm = 0; float bv = dd[0];
#pragma unroll
        for (int s = 1; s < KNNK; s++) if (dd[s] > bv) { bv = dd[s]; sm = s; }
#pragma unroll
        for (int s = 0; s < KNNK; s++) if (s == sm) { dd[s] = d2; ii[s] = ci[j]; }
        mx = dd[0];
#pragma unroll
        for (int s = 1; s < KNNK; s++) mx = fmaxf(mx, dd[s]);
      }
    }
  }
  for (int j = 0; j < KNNK; j++) knn[((size_t)(b * K + k)) * KNNK + j] = ii[j];
}

// ---------------------------------------------------------------------------
// Phase 3: gather 16 neighbor feature rows, mean, 32x32 linear.
// ---------------------------------------------------------------------------
__global__ __launch_bounds__(256) void k_extract(
    const float* __restrict__ f, const int* __restrict__ knn,
    const float* __restrict__ We, float* __restrict__ out) {
  __shared__ float P[8][C + 1];
  int tid = threadIdx.x;
  int kp = tid >> 5, c = tid & 31;
  int gk = blockIdx.x * 8 + kp;   // 0..2047
  int b = gk >> 8;
  float s = 0.f;
#pragma unroll
  for (int j = 0; j < KNNK; j++) {
    int pl = knn[(size_t)gk * KNNK + j];
    s += f[((size_t)(b * NPTS + pl)) * C + c];
  }
  P[kp][c] = s * (1.f / KNNK);
  __syncthreads();
  float r = 0.f;
#pragma unroll
  for (int cc = 0; cc < C; cc++) r += P[kp][cc] * We[cc * C + c];
  out[(size_t)gk * C + c] = r;
}

extern "C" void kernel_launch(void* const* d_in, const int* in_sizes, int n_in,
                              void* d_out, int out_size, void* d_ws, size_t ws_size,
                              hipStream_t stream) {
  const float* f   = (const float*)d_in[0];
  const float* pos = (const float*)d_in[1];
  // d_in[2] = W_pool: mathematically unused (bias cancels in segment softmax)
  const float* Wr  = (const float*)d_in[3];
  const float* We  = (const float*)d_in[4];
  float* out = (float*)d_out;

  char* ws = (char*)d_ws;
  float*    partials  = (float*)(ws + 0);        // [8][256][4][4] f32 = 131072 B
  float*    keypoints = (float*)(ws + 131072);   // [8][256][3] f32  = 24576 B
  float*    centers   = (float*)(ws + 155648);   // [8][4] f32       = 128 B
  unsigned* hist      = (unsigned*)(ws + 155776);// [8][512] u32     = 16384 B
  float*    Rf2       = (float*)(ws + 172160);   // [8] f32          = 32 B
  unsigned* cnt       = (unsigned*)(ws + 172192);// [8] u32          = 32 B
  int*      cand      = (int*)(ws + 172224);     // [8][16384] i32   = 524288 B
  int*      knn       = (int*)(ws + 696512);     // [8][256][16] i32 = 131072 B

  k_logits <<<dim3(BS * (K / KT) * NSPLIT), dim3(256), 0, stream>>>(f, pos, Wr, partials);
  k_centers<<<dim3(BS),  dim3(256), 0, stream>>>(partials, keypoints, centers, hist, cnt);
  k_hist   <<<dim3(BS * 8), dim3(256), 0, stream>>>(pos, centers, hist);
  k_select <<<dim3(BS),  dim3(64),  0, stream>>>(hist, centers, Rf2);
  k_compact<<<dim3(BS * 8), dim3(256), 0, stream>>>(pos, centers, Rf2, cnt, cand);
  k_knn    <<<dim3(BS),  dim3(256), 0, stream>>>(pos, keypoints, cnt, cand, knn);
  k_extract<<<dim3((BS * K) / 8), dim3(256), 0, stream>>>(f, knn, We, out);
}

// Round 2
// 215.012 us; speedup vs baseline: 2.3499x; 2.3499x over previous
//
#include <hip/hip_runtime.h>
#include <math.h>

#define BS 8
#define NPTS 16384
#define C 32
#define K 256
#define KNNK 16
#define NBINS 512
#define BINW 0.00025f

// ---------------------------------------------------------------------------
// Phase 1: fused regression-logit GEMM + exp + weighted position accumulation.
// Thread = keypoint-pair (t, t+128); block = one disjoint point-chunk.
// W columns live in registers; per-point features are wave-uniform loads
// (all 64 lanes same address -> single 16B request, HW broadcast).
// Pooling-head bias is constant over n and cancels in the segment softmax, so
// W_pool / glob / batched are never computed. Logits bounded (|L|<~4), so
// exp() without max-subtraction is safe and partials merge across blocks.
// ---------------------------------------------------------------------------
__global__ __launch_bounds__(128, 2) void k_logits(
    const float* __restrict__ f, const float* __restrict__ pos,
    const float* __restrict__ Wr, float* __restrict__ partials, int nsplit) {
  int b = blockIdx.x / nsplit;
  int split = blockIdx.x % nsplit;
  int chunk = NPTS / nsplit;
  int t = threadIdx.x;   // 0..127; handles keypoints t and t+128

  float w0[C], w1[C];
#pragma unroll
  for (int c = 0; c < C; c++) {
    w0[c] = Wr[c * K + t];
    w1[c] = Wr[c * K + t + 128];
  }

  float l0s = 0.f, x0s = 0.f, y0s = 0.f, z0s = 0.f;
  float l1s = 0.f, x1s = 0.f, y1s = 0.f, z1s = 0.f;

  int pbase = b * NPTS + split * chunk;
  const float4* fb = (const float4*)(f + (size_t)pbase * C);
  const float* pb = pos + (size_t)pbase * 3;

#pragma unroll 2
  for (int p = 0; p < chunk; p++) {
    float4 fv[8];
#pragma unroll
    for (int q = 0; q < 8; q++) fv[q] = fb[(size_t)p * 8 + q];
    float l0 = 0.f, l1 = 0.f;
#pragma unroll
    for (int q = 0; q < 8; q++) {
      l0 += fv[q].x * w0[4*q] + fv[q].y * w0[4*q+1] + fv[q].z * w0[4*q+2] + fv[q].w * w0[4*q+3];
      l1 += fv[q].x * w1[4*q] + fv[q].y * w1[4*q+1] + fv[q].z * w1[4*q+2] + fv[q].w * w1[4*q+3];
    }
    float e0 = __expf(l0), e1 = __expf(l1);
    float px = pb[p*3+0], py = pb[p*3+1], pz = pb[p*3+2];
    l0s += e0; x0s += e0 * px; y0s += e0 * py; z0s += e0 * pz;
    l1s += e1; x1s += e1 * px; y1s += e1 * py; z1s += e1 * pz;
  }

  float4* po = (float4*)partials;
  po[(size_t)blockIdx.x * 256 + t * 2 + 0] = make_float4(l0s, x0s, y0s, z0s);
  po[(size_t)blockIdx.x * 256 + t * 2 + 1] = make_float4(l1s, x1s, y1s, z1s);
}

// ---------------------------------------------------------------------------
// Phase 1b: merge partials (fp64) -> keypoints; per-graph keypoint centroid +
// max diameter for the KNN candidate filter; zero hist / candidate counters.
// ---------------------------------------------------------------------------
__global__ __launch_bounds__(256) void k_centers(
    const float* __restrict__ partials, float* __restrict__ keypoints,
    float* __restrict__ centers, unsigned* __restrict__ hist,
    unsigned* __restrict__ cnt, int nsplit) {
  int b = blockIdx.x;
  int k = threadIdx.x;
  int slot = (k & 127) * 2 + (k >> 7);
  const float4* po = (const float4*)partials;
  double L = 0, X = 0, Y = 0, Z = 0;
  for (int s = 0; s < nsplit; s++) {
    float4 v = po[(size_t)(b * nsplit + s) * 256 + slot];
    L += (double)v.x; X += (double)v.y; Y += (double)v.z; Z += (double)v.w;
  }
  float kx = (float)(X / L), ky = (float)(Y / L), kz = (float)(Z / L);
  keypoints[(b * K + k) * 3 + 0] = kx;
  keypoints[(b * K + k) * 3 + 1] = ky;
  keypoints[(b * K + k) * 3 + 2] = kz;
  hist[b * NBINS + k] = 0;
  hist[b * NBINS + K + k] = 0;
  if (k == 0) cnt[b] = 0;

  __shared__ float red[256];
  red[k] = kx; __syncthreads();
  for (int s = 128; s; s >>= 1) { if (k < s) red[k] += red[k + s]; __syncthreads(); }
  float cx = red[0] / K; __syncthreads();
  red[k] = ky; __syncthreads();
  for (int s = 128; s; s >>= 1) { if (k < s) red[k] += red[k + s]; __syncthreads(); }
  float cy = red[0] / K; __syncthreads();
  red[k] = kz; __syncthreads();
  for (int s = 128; s; s >>= 1) { if (k < s) red[k] += red[k + s]; __syncthreads(); }
  float cz = red[0] / K; __syncthreads();
  float dx = kx - cx, dy = ky - cy, dz = kz - cz;
  red[k] = dx * dx + dy * dy + dz * dz; __syncthreads();
  for (int s = 128; s; s >>= 1) { if (k < s) red[k] = fmaxf(red[k], red[k + s]); __syncthreads(); }
  if (k == 0) {
    centers[b * 4 + 0] = cx; centers[b * 4 + 1] = cy; centers[b * 4 + 2] = cz;
    centers[b * 4 + 3] = sqrtf(red[0]);   // max dist keypoint->centroid
  }
}

// ---------------------------------------------------------------------------
// Phase 2a: histogram of d2(point, centroid) per graph.
// ---------------------------------------------------------------------------
__global__ __launch_bounds__(256) void k_hist(
    const float* __restrict__ pos, const float* __restrict__ centers,
    unsigned* __restrict__ hist) {
  __shared__ unsigned lh[NBINS];
  int b = blockIdx.x >> 3, part = blockIdx.x & 7;
  for (int t = threadIdx.x; t < NBINS; t += 256) lh[t] = 0;
  __syncthreads();
  float cx = centers[b * 4 + 0], cy = centers[b * 4 + 1], cz = centers[b * 4 + 2];
  for (int i = 0; i < 8; i++) {
    int p = b * NPTS + part * 2048 + i * 256 + threadIdx.x;
    float dx = pos[p * 3 + 0] - cx, dy = pos[p * 3 + 1] - cy, dz = pos[p * 3 + 2] - cz;
    float d2 = dx * dx + dy * dy + dz * dz;
    int bin = (int)(d2 * (1.0f / BINW));
    if (bin > NBINS - 1) bin = NBINS - 1;
    atomicAdd(&lh[bin], 1u);
  }
  __syncthreads();
  for (int t = threadIdx.x; t < NBINS; t += 256)
    if (lh[t]) atomicAdd(&hist[b * NBINS + t], lh[t]);
}

// ---------------------------------------------------------------------------
// Phase 2b: candidate radius. Exact bound: any point in some keypoint's top-16
// satisfies d(p,c) <= T + 2*maxdiam with T >= 16th-smallest d(.,c). Catch-all
// bin (T=inf) degenerates to keeping everything -> always correct.
// ---------------------------------------------------------------------------
__global__ void k_select(const unsigned* __restrict__ hist,
                         const float* __restrict__ centers,
                         float* __restrict__ Rf2) {
  int b = blockIdx.x;
  if (threadIdx.x == 0) {
    unsigned cum = 0; float T2 = 1e30f;
    for (int i = 0; i < NBINS; i++) {
      cum += hist[b * NBINS + i];
      if (cum >= KNNK) { T2 = (i + 1) * BINW; break; }
    }
    float Rf = sqrtf(T2) + 2.f * centers[b * 4 + 3];
    Rf2[b] = Rf * Rf;
  }
}

// ---------------------------------------------------------------------------
// Phase 2c: compact candidate indices (order irrelevant: KNN is a set).
// ---------------------------------------------------------------------------
__global__ __launch_bounds__(256) void k_compact(
    const float* __restrict__ pos, const float* __restrict__ centers,
    const float* __restrict__ Rf2, unsigned* __restrict__ cnt,
    int* __restrict__ cand) {
  int b = blockIdx.x >> 3, part = blockIdx.x & 7;
  float r2 = Rf2[b];
  float cx = centers[b * 4 + 0], cy = centers[b * 4 + 1], cz = centers[b * 4 + 2];
  for (int i = 0; i < 8; i++) {
    int pl = part * 2048 + i * 256 + threadIdx.x;
    int p = b * NPTS + pl;
    float dx = pos[p * 3 + 0] - cx, dy = pos[p * 3 + 1] - cy, dz = pos[p * 3 + 2] - cz;
    float d2 = dx * dx + dy * dy + dz * dz;
    if (d2 <= r2) {
      unsigned s = atomicAdd(&cnt[b], 1u);
      cand[b * NPTS + s] = pl;
    }
  }
}

// ---------------------------------------------------------------------------
// Phase 2d: exact top-16 (smallest d2) per keypoint over candidates.
// ---------------------------------------------------------------------------
__global__ __launch_bounds__(256) void k_knn(
    const float* __restrict__ pos, const float* __restrict__ keypoints,
    const unsigned* __restrict__ cnt, const int* __restrict__ cand,
    int* __restrict__ knn) {
  int b = blockIdx.x;
  int k = threadIdx.x;
  __shared__ float4 cp[1024];
  __shared__ int ci[1024];
  float kx = keypoints[(b * K + k) * 3 + 0];
  float ky = keypoints[(b * K + k) * 3 + 1];
  float kz = keypoints[(b * K + k) * 3 + 2];
  float dd[KNNK]; int ii[KNNK];
#pragma unroll
  for (int j = 0; j < KNNK; j++) { dd[j] = 1e30f; ii[j] = 0; }
  float mx = 1e30f;
  int n = (int)cnt[b];
  if (n > NPTS) n = NPTS;
  for (int c0 = 0; c0 < n; c0 += 1024) {
    int m = min(1024, n - c0);
    __syncthreads();
    for (int j = threadIdx.x; j < m; j += 256) {
      int pl = cand[b * NPTS + c0 + j];
      const float* pp = pos + (size_t)(b * NPTS + pl) * 3;
      cp[j] = make_float4(pp[0], pp[1], pp[2], 0.f);
      ci[j] = pl;
    }
    __syncthreads();
    for (int j = 0; j < m; j++) {
      float4 q = cp[j];
      float dx = kx - q.x, dy = ky - q.y, dz = kz - q.z;
      float d2 = dx * dx + dy * dy + dz * dz;
      if (d2 < mx) {
        int sm = 0; float bv = dd[0];
#pragma unroll
        for (int s = 1; s < KNNK; s++) if (dd[s] > bv) { bv = dd[s]; sm = s; }
#pragma unroll
        for (int s = 0; s < KNNK; s++) if (s == sm) { dd[s] = d2; ii[s] = ci[j]; }
        mx = dd[0];
#pragma unroll
        for (int s = 1; s < KNNK; s++) mx = fmaxf(mx, dd[s]);
      }
    }
  }
  for (int j = 0; j < KNNK; j++) knn[((size_t)(b * K + k)) * KNNK + j] = ii[j];
}

// ---------------------------------------------------------------------------
// Phase 3: gather 16 neighbor feature rows, mean, 32x32 linear.
// ---------------------------------------------------------------------------
__global__ __launch_bounds__(256) void k_extract(
    const float* __restrict__ f, const int* __restrict__ knn,
    const float* __restrict__ We, float* __restrict__ out) {
  __shared__ float P[8][C + 1];
  int tid = threadIdx.x;
  int kp = tid >> 5, c = tid & 31;
  int gk = blockIdx.x * 8 + kp;   // 0..2047
  int b = gk >> 8;
  float s = 0.f;
#pragma unroll
  for (int j = 0; j < KNNK; j++) {
    int pl = knn[(size_t)gk * KNNK + j];
    s += f[((size_t)(b * NPTS + pl)) * C + c];
  }
  P[kp][c] = s * (1.f / KNNK);
  __syncthreads();
  float r = 0.f;
#pragma unroll
  for (int cc = 0; cc < C; cc++) r += P[kp][cc] * We[cc * C + c];
  out[(size_t)gk * C + c] = r;
}

extern "C" void kernel_launch(void* const* d_in, const int* in_sizes, int n_in,
                              void* d_out, int out_size, void* d_ws, size_t ws_size,
                              hipStream_t stream) {
  const float* f   = (const float*)d_in[0];
  const float* pos = (const float*)d_in[1];
  // d_in[2] = W_pool: mathematically unused (bias cancels in segment softmax)
  const float* Wr  = (const float*)d_in[3];
  const float* We  = (const float*)d_in[4];
  float* out = (float*)d_out;

  // nsplit=128: partials = BS*128 blocks * 256 float4 = 4 MiB. Fall back to a
  // smaller split (1 MiB) if the workspace is tight.
  size_t fixed = 24576 + 128 + 16384 + 32 + 32 + 524288 + 131072; // ~700 KB
  int nsplit = (ws_size >= (size_t)(4u << 20) + fixed + 4096) ? 128 : 32;
  size_t partials_bytes = (size_t)BS * nsplit * 256 * 16;

  char* ws = (char*)d_ws;
  float*    partials  = (float*)(ws + 0);
  char*     base      = ws + partials_bytes;
  float*    keypoints = (float*)(base + 0);        // [8][256][3] f32  = 24576 B
  float*    centers   = (float*)(base + 24576);    // [8][4] f32       = 128 B
  unsigned* hist      = (unsigned*)(base + 24704); // [8][512] u32     = 16384 B
  float*    Rf2       = (float*)(base + 41088);    // [8] f32          = 32 B
  unsigned* cnt       = (unsigned*)(base + 41120); // [8] u32          = 32 B
  int*      cand      = (int*)(base + 41152);      // [8][16384] i32   = 524288 B
  int*      knn       = (int*)(base + 565440);     // [8][256][16] i32 = 131072 B

  k_logits <<<dim3(BS * nsplit), dim3(128), 0, stream>>>(f, pos, Wr, partials, nsplit);
  k_centers<<<dim3(BS),  dim3(256), 0, stream>>>(partials, keypoints, centers, hist, cnt, nsplit);
  k_hist   <<<dim3(BS * 8), dim3(256), 0, stream>>>(pos, centers, hist);
  k_select <<<dim3(BS),  dim3(64),  0, stream>>>(hist, centers, Rf2);
  k_compact<<<dim3(BS * 8), dim3(256), 0, stream>>>(pos, centers, Rf2, cnt, cand);
  k_knn    <<<dim3(BS),  dim3(256), 0, stream>>>(pos, keypoints, cnt, cand, knn);
  k_extract<<<dim3((BS * K) / 8), dim3(256), 0, stream>>>(f, knn, We, out);
}